// Round 7
// baseline (1229.057 us; speedup 1.0000x reference)
//
#include <hip/hip_runtime.h>
#include <hip/hip_bf16.h>

#define SEQ   2048
#define BATCH 512
#define INPT  64
#define HID   128
#define KTOT  192   // 64 x + 128 h
#define NSL   8     // k-slices
#define KSH   24    // k per slice
#define NOUT  4     // outputs per thread

typedef _Float16 half2_t __attribute__((ext_vector_type(2)));
typedef _Float16 half4_t __attribute__((ext_vector_type(4)));
typedef float    float4_t __attribute__((ext_vector_type(4)));

#if defined(__has_builtin)
#if __has_builtin(__builtin_amdgcn_fdot2)
#define HAVE_FDOT2 1
#endif
#endif

__device__ __forceinline__ float fdot2f(half2_t a, half2_t b, float c) {
#ifdef HAVE_FDOT2
    return __builtin_amdgcn_fdot2(a, b, c, false);
#else
    return fmaf((float)a[0], (float)b[0], fmaf((float)a[1], (float)b[1], c));
#endif
}

// xor-neighbor add within quads via DPP (VALU pipe, not LDS pipe).
// CTRL must be an immediate -> template parameter.
template <int CTRL>
__device__ __forceinline__ float dpp_xor_add(float v) {
    int x = __builtin_amdgcn_update_dpp(0, __builtin_bit_cast(int, v), CTRL, 0xF, 0xF, true);
    return v + __builtin_bit_cast(float, x);
}
// xor-4 lane add via ds_swizzle (BitMode: (4<<10)|0x1F)
__device__ __forceinline__ float swz_xor4_add(float v) {
    int x = __builtin_amdgcn_ds_swizzle(__builtin_bit_cast(int, v), 0x101F);
    return v + __builtin_bit_cast(float, x);
}

__device__ __forceinline__ float tanh_fast(float a) {
    // tanh(a) = 1 - 2/(exp(2a)+1); saturates correctly at +/-inf
    float e = __expf(2.0f * a);
    float r = __builtin_amdgcn_rcpf(e + 1.0f);
    return fmaf(-2.0f, r, 1.0f);
}

__global__ __launch_bounds__(256, 2) void rnn_kernel(
    const float* __restrict__ xs,   const float* __restrict__ W_ih,
    const float* __restrict__ W_hh, const float* __restrict__ b_ih,
    const float* __restrict__ b_hh, const float* __restrict__ W_out,
    const float* __restrict__ b_out, float* __restrict__ out)
{
    const int row = blockIdx.x;          // batch row, 0..511
    const int tid = threadIdx.x;         // 0..255
    const int s   = tid & (NSL - 1);     // k-slice 0..7
    const int jg  = tid >> 3;            // output group 0..31 (outputs 4jg..4jg+3)
    const int k0  = s * KSH;             // start k of this thread's slice

    __shared__ alignas(16) _Float16 F[2][KTOT];  // [x(64); h(128)], double buffered

    // ---- weights: f16-packed, resident in VGPRs (48 half2 regs) ----
    half2_t w[NOUT][KSH / 2];
    float bsum[NOUT];
    #pragma unroll
    for (int c = 0; c < NOUT; ++c) {
        const int r = jg * NOUT + c;
        bsum[c] = b_ih[r] + b_hh[r];
        #pragma unroll
        for (int p = 0; p < KSH / 2; ++p) {
            int k = k0 + 2 * p;   // always even; x/h boundary (64) never splits a pair
            float w0 = (k     < 64) ? W_ih[r * INPT + k]     : W_hh[r * HID + (k - 64)];
            float w1 = (k + 1 < 64) ? W_ih[r * INPT + k + 1] : W_hh[r * HID + (k + 1 - 64)];
            half2_t hw; hw[0] = (_Float16)w0; hw[1] = (_Float16)w1;
            w[c][p] = hw;
        }
    }

    // ---- init: h = 0, x(0) into F[0]; prefetch x(1), x(2) ----
    const float*  xrow    = xs + (size_t)row * INPT;
    const size_t  tstride = (size_t)BATCH * INPT;

    if (tid < 64) ((int*)&F[0][64])[tid] = 0;   // zero h region (128 halves)
    float4_t P0, P1;
    if (tid < 16) {
        float4_t x0 = *((const float4_t*)(xrow + 0 * tstride) + tid);
        half4_t h4; h4[0] = (_Float16)x0[0]; h4[1] = (_Float16)x0[1];
        h4[2] = (_Float16)x0[2]; h4[3] = (_Float16)x0[3];
        *(half4_t*)&F[0][4 * tid] = h4;
        P1 = *((const float4_t*)(xrow + 1 * tstride) + tid);  // x(1)
        P0 = *((const float4_t*)(xrow + 2 * tstride) + tid);  // x(2)
    }
    __syncthreads();

    auto step = [&](int t, int cur, int nxt, float4_t& P) {
        // broadcast-read this thread's 24 f16 of [x;h] (3x ds_read_b128, bank-disjoint)
        union { int4 i4[3]; half2_t h2[12]; } u;
        const int4* src = (const int4*)&F[cur][k0];   // 48 bytes, 16B aligned
        u.i4[0] = src[0]; u.i4[1] = src[1]; u.i4[2] = src[2];

        // accumulators start at ZERO: the xor-tree sums 8 lanes, so any bias
        // seeded here would be counted 8x (round-3 bug). Bias is added once,
        // by the writing lane, after the reduction.
        float a0 = 0.0f, a1 = 0.0f, a2 = 0.0f, a3 = 0.0f;
        #pragma unroll
        for (int p = 0; p < 12; ++p) {
            a0 = fdot2f(u.h2[p], w[0][p], a0);
            a1 = fdot2f(u.h2[p], w[1][p], a1);
            a2 = fdot2f(u.h2[p], w[2][p], a2);
            a3 = fdot2f(u.h2[p], w[3][p], a3);
        }
        // reduce across 8 slices: xor1,xor2 via DPP quad_perm; xor4 via ds_swizzle
        a0 = dpp_xor_add<0xB1>(a0); a0 = dpp_xor_add<0x4E>(a0); a0 = swz_xor4_add(a0);
        a1 = dpp_xor_add<0xB1>(a1); a1 = dpp_xor_add<0x4E>(a1); a1 = swz_xor4_add(a1);
        a2 = dpp_xor_add<0xB1>(a2); a2 = dpp_xor_add<0x4E>(a2); a2 = swz_xor4_add(a2);
        a3 = dpp_xor_add<0xB1>(a3); a3 = dpp_xor_add<0x4E>(a3); a3 = swz_xor4_add(a3);

        // lanes s==0 handle c0,c1; lanes s==4 handle c2,c3 (same code path => 2 tanh issues)
        float va = (s == 0) ? a0 + bsum[0] : a2 + bsum[2];
        float vb = (s == 0) ? a1 + bsum[1] : a3 + bsum[3];
        if ((s & 3) == 0) {
            float ha = tanh_fast(va);
            float hb = tanh_fast(vb);
            int off = 64 + jg * 4 + ((s >> 1) & 2);   // s==0 -> +0, s==4 -> +2
            half2_t hh; hh[0] = (_Float16)ha; hh[1] = (_Float16)hb;
            *(half2_t*)&F[nxt][off] = hh;
        }
        // consume prefetched x(t+1) -> F[nxt]; reissue prefetch for x(t+3)
        if (tid < 16) {
            half4_t h4; h4[0] = (_Float16)P[0]; h4[1] = (_Float16)P[1];
            h4[2] = (_Float16)P[2]; h4[3] = (_Float16)P[3];
            *(half4_t*)&F[nxt][4 * tid] = h4;
            if (t + 3 < SEQ)
                P = *((const float4_t*)(xrow + (size_t)(t + 3) * tstride) + tid);
        }
        __syncthreads();
    };

    for (int t2 = 0; t2 < SEQ; t2 += 2) {
        step(t2,     0, 1, P1);   // even t: reads F[0], writes F[1], consumes x(t+1) from P1
        step(t2 + 1, 1, 0, P0);   // odd  t: reads F[1], writes F[0], consumes x(t+1) from P0
    }

    // ---- epilogue: out[row] = h_final . W_out + b_out  (h_final in F[0]) ----
    if (tid < 64) {
        float p = (float)F[0][64 + tid]      * W_out[tid]
                + (float)F[0][64 + 64 + tid] * W_out[64 + tid];
        p += __shfl_xor(p, 1);  p += __shfl_xor(p, 2);  p += __shfl_xor(p, 4);
        p += __shfl_xor(p, 8);  p += __shfl_xor(p, 16); p += __shfl_xor(p, 32);
        if (tid == 0) out[row] = p + b_out[0];
    }
}

extern "C" void kernel_launch(void* const* d_in, const int* in_sizes, int n_in,
                              void* d_out, int out_size, void* d_ws, size_t ws_size,
                              hipStream_t stream) {
    const float* xs    = (const float*)d_in[0];
    const float* W_ih  = (const float*)d_in[1];
    const float* W_hh  = (const float*)d_in[2];
    const float* b_ih  = (const float*)d_in[3];
    const float* b_hh  = (const float*)d_in[4];
    const float* W_out = (const float*)d_in[5];
    const float* b_out = (const float*)d_in[6];
    float* out = (float*)d_out;

    rnn_kernel<<<dim3(BATCH), dim3(256), 0, stream>>>(
        xs, W_ih, W_hh, b_ih, b_hh, W_out, b_out, out);
}

// Round 8
// 1191.102 us; speedup vs baseline: 1.0319x; 1.0319x over previous
//
#include <hip/hip_runtime.h>

#define SEQ   2048
#define BATCH 512
#define INPT  64
#define HID   128
#define ROWS  16              // batch rows per block (MFMA M)
#define NBLK  (BATCH/ROWS)    // 32 blocks
#define CHUNK 16              // steps per x-chunk staged in LDS
#define XSTR  72              // x row stride in halves (pad for banks)
#define HSTR  136             // h row stride in halves (pad for banks)

typedef _Float16 f16x8 __attribute__((ext_vector_type(8)));
typedef _Float16 f16x4 __attribute__((ext_vector_type(4)));
typedef float    f32x4 __attribute__((ext_vector_type(4)));

__device__ __forceinline__ float tanh_fast(float a) {
    // tanh(a) = 1 - 2/(exp(2a)+1); exact saturation at +/-inf
    float e = __expf(2.0f * a);
    float r = __builtin_amdgcn_rcpf(e + 1.0f);
    return fmaf(-2.0f, r, 1.0f);
}

__global__ __launch_bounds__(512) void rnn_mfma(
    const float* __restrict__ xs,   const float* __restrict__ W_ih,
    const float* __restrict__ W_hh, const float* __restrict__ b_ih,
    const float* __restrict__ b_hh, const float* __restrict__ W_out,
    const float* __restrict__ b_out, float* __restrict__ out)
{
    const int tid  = threadIdx.x;
    const int lane = tid & 63;
    const int wv   = tid >> 6;       // wave 0..7
    const int n0   = wv * 16;        // N-slice base (hidden cols n0..n0+15)
    const int ml   = lane & 15;      // A-row m / B-col n selector
    const int kq   = lane >> 4;      // k-quad 0..3
    const int r0   = blockIdx.x * ROWS;

    // x chunks: [2][CHUNK][ROWS][XSTR] halves; h ping-pong: [2][ROWS][HSTR]
    __shared__ _Float16 xb[2][CHUNK * ROWS * XSTR];   // 73728 B
    __shared__ _Float16 hb[2][ROWS * HSTR];           //  8704 B

    // ---- B fragments (weights) resident in VGPRs: 6 k-tiles of 32 ----
    // B[k][n] = Wcat[n0+ml][k];  lane holds k = kt*32 + kq*8 + j
    f16x8 bf[6];
    {
        const int n = n0 + ml;
        #pragma unroll
        for (int kt = 0; kt < 6; ++kt) {
            f16x8 v;
            #pragma unroll
            for (int j = 0; j < 8; ++j) {
                int k = kt * 32 + kq * 8 + j;
                float wval = (k < 64) ? W_ih[n * INPT + k] : W_hh[n * HID + (k - 64)];
                v[j] = (_Float16)wval;
            }
            bf[kt] = v;
        }
    }
    const float bias = b_ih[n0 + ml] + b_hh[n0 + ml];   // depends on n only

    // ---- zero h0 ----
    for (int i = tid; i < ROWS * 64; i += 512) {        // 64 words per row
        int m = i >> 6, w = i & 63;
        ((int*)&hb[0][m * HSTR])[w] = 0;
    }

    // ---- stage x chunk 0; staging map: thread -> (sts, 8 float4 tiles) ----
    const int sts  = tid >> 5;       // step-in-chunk 0..15
    const int srem = tid & 31;
    f32x4 st[8];
    #pragma unroll
    for (int j = 0; j < 8; ++j) {
        int flat = srem + 32 * j, m = flat >> 4, e4 = flat & 15;
        st[j] = *(const f32x4*)&xs[((size_t)sts * BATCH + r0 + m) * INPT + e4 * 4];
    }
    #pragma unroll
    for (int j = 0; j < 8; ++j) {
        int flat = srem + 32 * j, m = flat >> 4, e4 = flat & 15;
        f16x4 o; o[0] = (_Float16)st[j][0]; o[1] = (_Float16)st[j][1];
                 o[2] = (_Float16)st[j][2]; o[3] = (_Float16)st[j][3];
        *(f16x4*)&xb[0][(sts * ROWS + m) * XSTR + e4 * 4] = o;
    }
    __syncthreads();

    // ---- recurrence ----
    for (int t = 0; t < SEQ; ++t) {
        const int kc  = t & (CHUNK - 1);
        const int cb  = (t >> 4) & 1;
        const int hbi = t & 1;

        // A fragments: A[m][k], m=ml, k = kt*32 + kq*8 + j
        const _Float16* xr = &xb[cb][(kc * ROWS + ml) * XSTR + kq * 8];
        f16x8 a0 = *(const f16x8*)(xr);
        f16x8 a1 = *(const f16x8*)(xr + 32);
        const _Float16* hr = &hb[hbi][ml * HSTR + kq * 8];
        f16x8 a2 = *(const f16x8*)(hr);
        f16x8 a3 = *(const f16x8*)(hr + 32);
        f16x8 a4 = *(const f16x8*)(hr + 64);
        f16x8 a5 = *(const f16x8*)(hr + 96);

        // issue next-chunk global loads (stay in flight across raw barriers)
        if (kc == 0 && t + CHUNK < SEQ) {
            #pragma unroll
            for (int j = 0; j < 8; ++j) {
                int flat = srem + 32 * j, m = flat >> 4, e4 = flat & 15;
                st[j] = *(const f32x4*)&xs[((size_t)(t + CHUNK + sts) * BATCH + r0 + m) * INPT + e4 * 4];
            }
        }

        // two independent 3-chains of MFMA over K
        f32x4 acc1 = {0.f, 0.f, 0.f, 0.f}, acc2 = {0.f, 0.f, 0.f, 0.f};
        acc1 = __builtin_amdgcn_mfma_f32_16x16x32_f16(a0, bf[0], acc1, 0, 0, 0);
        acc2 = __builtin_amdgcn_mfma_f32_16x16x32_f16(a1, bf[1], acc2, 0, 0, 0);
        acc1 = __builtin_amdgcn_mfma_f32_16x16x32_f16(a2, bf[2], acc1, 0, 0, 0);
        acc2 = __builtin_amdgcn_mfma_f32_16x16x32_f16(a3, bf[3], acc2, 0, 0, 0);
        acc1 = __builtin_amdgcn_mfma_f32_16x16x32_f16(a4, bf[4], acc1, 0, 0, 0);
        acc2 = __builtin_amdgcn_mfma_f32_16x16x32_f16(a5, bf[5], acc2, 0, 0, 0);

        // h_new: D[m = kq*4+q][n = n0+ml]  (m89-verified C/D layout)
        _Float16* hw = &hb[hbi ^ 1][0];
        #pragma unroll
        for (int q = 0; q < 4; ++q) {
            float v  = acc1[q] + acc2[q] + bias;
            float hv = tanh_fast(v);
            hw[(kq * 4 + q) * HSTR + n0 + ml] = (_Float16)hv;
        }

        // mid-chunk: commit staged x for next chunk (loads ~8 steps old)
        if (kc == 8 && t + 8 < SEQ) {
            #pragma unroll
            for (int j = 0; j < 8; ++j) {
                int flat = srem + 32 * j, m = flat >> 4, e4 = flat & 15;
                f16x4 o; o[0] = (_Float16)st[j][0]; o[1] = (_Float16)st[j][1];
                         o[2] = (_Float16)st[j][2]; o[3] = (_Float16)st[j][3];
                *(f16x4*)&xb[cb ^ 1][(sts * ROWS + m) * XSTR + e4 * 4] = o;
            }
        }

        // raw barrier: drain LDS only; global prefetch stays in flight (T4)
        asm volatile("s_waitcnt lgkmcnt(0)" ::: "memory");
        __builtin_amdgcn_s_barrier();
        __builtin_amdgcn_sched_barrier(0);
    }

    // ---- epilogue: out[r] = h_final . W_out + b_out; final h in hb[0] ----
    {
        const int m = tid >> 5, c = tid & 31;
        float p = 0.f;
        #pragma unroll
        for (int j = 0; j < 4; ++j) {
            int n = c * 4 + j;
            p += (float)hb[0][m * HSTR + n] * W_out[n];
        }
        p += __shfl_xor(p, 1); p += __shfl_xor(p, 2); p += __shfl_xor(p, 4);
        p += __shfl_xor(p, 8); p += __shfl_xor(p, 16);
        if (c == 0) out[r0 + m] = p + b_out[0];
    }
}

extern "C" void kernel_launch(void* const* d_in, const int* in_sizes, int n_in,
                              void* d_out, int out_size, void* d_ws, size_t ws_size,
                              hipStream_t stream) {
    const float* xs    = (const float*)d_in[0];
    const float* W_ih  = (const float*)d_in[1];
    const float* W_hh  = (const float*)d_in[2];
    const float* b_ih  = (const float*)d_in[3];
    const float* b_hh  = (const float*)d_in[4];
    const float* W_out = (const float*)d_in[5];
    const float* b_out = (const float*)d_in[6];
    float* out = (float*)d_out;

    rnn_mfma<<<dim3(NBLK), dim3(512), 0, stream>>>(
        xs, W_ih, W_hh, b_ih, b_hh, W_out, b_out, out);
}